// Round 2
// baseline (2454.598 us; speedup 1.0000x reference)
//
#include <hip/hip_runtime.h>

// ---------------------------------------------------------------------------
// AttentionDecoder: 32-step GRU decoder with dual dot-product attention.
// Structure:
//   prologue: bf16 weight converts; ctx->h0 (MFMA, split-K); keys/vals
//             projections (MFMA, K=4096); W_f = W_ih@W_in fold; gi_x precompute
//   loop t=0..31:  phaseX (GRU elementwise for t-1, q=tanh(h Wq), softmax attn)
//                  phaseY (MFMA: gi = att@Wf^T + gi_x + bfull ; gh = h@Whh^T)
//   epilogue: final GRU elementwise; vocab GEMM (MFMA) -> d_out (f32)
// ---------------------------------------------------------------------------

typedef float    f32x4 __attribute__((ext_vector_type(4)));
typedef __bf16   bf16x8 __attribute__((ext_vector_type(8)));
typedef unsigned short u16x8 __attribute__((ext_vector_type(8)));

#define DEV __device__ __forceinline__

DEV unsigned short f2bf(float f) {
  unsigned u = __builtin_bit_cast(unsigned, f);
  u += 0x7fffu + ((u >> 16) & 1u);               // round-to-nearest-even
  return (unsigned short)(u >> 16);
}
DEV float bf2f(unsigned short h) {
  return __builtin_bit_cast(float, (unsigned)h << 16);
}
DEV bf16x8 as_bf(u16x8 v) { return __builtin_bit_cast(bf16x8, v); }
DEV u16x8 zero8() {
  u16x8 r = {0, 0, 0, 0, 0, 0, 0, 0};
  return r;
}
DEV u16x8 pack8(float4 a, float4 b) {
  u16x8 r;
  r[0]=f2bf(a.x); r[1]=f2bf(a.y); r[2]=f2bf(a.z); r[3]=f2bf(a.w);
  r[4]=f2bf(b.x); r[5]=f2bf(b.y); r[6]=f2bf(b.z); r[7]=f2bf(b.w);
  return r;
}

// ------------------------------- converts ----------------------------------
__global__ __launch_bounds__(256) void k_cvt(const float* __restrict__ s,
                                             unsigned short* __restrict__ d, int n) {
  int i = (blockIdx.x * 256 + threadIdx.x) * 4;
  if (i + 4 <= n) {
    float4 v = *(const float4*)(s + i);
    d[i] = f2bf(v.x); d[i+1] = f2bf(v.y); d[i+2] = f2bf(v.z); d[i+3] = f2bf(v.w);
  } else {
    for (; i < n; i++) d[i] = f2bf(s[i]);
  }
}

// ctx_feat = [s1, s2, |s1-s2|, s1*s2]  -> bf16 [64, 16384]
__global__ __launch_bounds__(256) void k_build_ctx(const float* __restrict__ s1,
                                                   const float* __restrict__ s2,
                                                   unsigned short* __restrict__ ctx) {
  int j = blockIdx.x * 256 + threadIdx.x;     // < 64*16384
  int b = j >> 14, jj = j & 16383;
  int f = jj >> 12, k = jj & 4095;
  float a = s1[b * 4096 + k], c = s2[b * 4096 + k];
  float v = (f == 0) ? a : (f == 1) ? c : (f == 2) ? fabsf(a - c) : a * c;
  ctx[j] = f2bf(v);
}

// ------------------------- generic 128x128 MFMA GEMM ------------------------
// C[M,N] = A[M,K] * B[N,K]^T ; EPI 0: tanh(+bias)->bf16 split keys/vals
//                              EPI 1: +bias -> f32 out
//                              EPI 2: raw -> f32 partials (split-K via z)
template<int A_BF16, int B_BF16, int EPI>
__global__ __launch_bounds__(256) void k_gemm128(
    const void* __restrict__ Ap, int lda, const void* __restrict__ Bp, int ldb,
    int M, int N, int kper,
    unsigned short* __restrict__ obf0, unsigned short* __restrict__ obf1,
    float* __restrict__ of, const float* __restrict__ bias0,
    const float* __restrict__ bias1)
{
  __shared__ __align__(16) unsigned short As[128 * 32];
  __shared__ __align__(16) unsigned short Bs[128 * 32];
  const int tid = threadIdx.x;
  const int c0 = blockIdx.x * 128, r0 = blockIdx.y * 128;
  const int k0 = blockIdx.z * kper;
  if (EPI == 2) of += (size_t)blockIdx.z * M * N;

  const int lane = tid & 63, w = tid >> 6;
  const int wr = w >> 1, wc = w & 1;
  const int fr = lane & 15, fq = lane >> 4;

  f32x4 acc[4][4] = {};

  const int srow = tid >> 1, shalf = (tid & 1) * 16;

  for (int k = k0; k < k0 + kper; k += 32) {
    u16x8 a0, a1, b0, b1;
    {
      int gr = r0 + srow;
      if (gr < M) {
        if (A_BF16) {
          const unsigned short* a = (const unsigned short*)Ap + (size_t)gr * lda + k + shalf;
          a0 = *(const u16x8*)a; a1 = *(const u16x8*)(a + 8);
        } else {
          const float* a = (const float*)Ap + (size_t)gr * lda + k + shalf;
          float4 f0 = ((const float4*)a)[0], f1 = ((const float4*)a)[1];
          float4 f2 = ((const float4*)a)[2], f3 = ((const float4*)a)[3];
          a0 = pack8(f0, f1); a1 = pack8(f2, f3);
        }
      } else { a0 = zero8(); a1 = zero8(); }
    }
    {
      int gr = c0 + srow;   // always < N (N multiple of 128)
      if (B_BF16) {
        const unsigned short* p = (const unsigned short*)Bp + (size_t)gr * ldb + k + shalf;
        b0 = *(const u16x8*)p; b1 = *(const u16x8*)(p + 8);
      } else {
        const float* p = (const float*)Bp + (size_t)gr * ldb + k + shalf;
        float4 f0 = ((const float4*)p)[0], f1 = ((const float4*)p)[1];
        float4 f2 = ((const float4*)p)[2], f3 = ((const float4*)p)[3];
        b0 = pack8(f0, f1); b1 = pack8(f2, f3);
      }
    }
    *(u16x8*)&As[srow * 32 + shalf]     = a0;
    *(u16x8*)&As[srow * 32 + shalf + 8] = a1;
    *(u16x8*)&Bs[srow * 32 + shalf]     = b0;
    *(u16x8*)&Bs[srow * 32 + shalf + 8] = b1;
    __syncthreads();

    u16x8 af[4], bfv[4];
    #pragma unroll
    for (int mi = 0; mi < 4; mi++)
      af[mi] = *(const u16x8*)&As[(wr * 64 + mi * 16 + fr) * 32 + fq * 8];
    #pragma unroll
    for (int nj = 0; nj < 4; nj++)
      bfv[nj] = *(const u16x8*)&Bs[(wc * 64 + nj * 16 + fr) * 32 + fq * 8];
    #pragma unroll
    for (int mi = 0; mi < 4; mi++)
      #pragma unroll
      for (int nj = 0; nj < 4; nj++)
        acc[mi][nj] = __builtin_amdgcn_mfma_f32_16x16x32_bf16(
            as_bf(af[mi]), as_bf(bfv[nj]), acc[mi][nj], 0, 0, 0);
    __syncthreads();
  }

  #pragma unroll
  for (int mi = 0; mi < 4; mi++)
  #pragma unroll
  for (int nj = 0; nj < 4; nj++) {
    f32x4 a = acc[mi][nj];
    #pragma unroll
    for (int j = 0; j < 4; j++) {
      int grow = r0 + wr * 64 + mi * 16 + fq * 4 + j;
      int gcol = c0 + wc * 64 + nj * 16 + fr;
      if (grow < M) {
        float v = a[j];
        if constexpr (EPI == 0) {
          float bias = gcol < 512 ? bias0[gcol] : bias1[gcol - 512];
          unsigned short r = f2bf(tanhf(v + bias));
          (gcol < 512 ? obf0 : obf1)[(size_t)grow * 512 + (gcol & 511)] = r;
        } else if constexpr (EPI == 1) {
          of[(size_t)grow * N + gcol] = v + bias0[gcol];
        } else {
          of[(size_t)grow * N + gcol] = v;
        }
      }
    }
  }
}

__global__ __launch_bounds__(256) void k_reduce_h0(const float* __restrict__ part,
                                                   const float* __restrict__ b_ctx,
                                                   float* __restrict__ h) {
  int j = blockIdx.x * 256 + threadIdx.x;   // < 64*512
  float s = b_ctx[j & 511];
  for (int z = 0; z < 8; z++) s += part[z * 32768 + j];
  h[j] = s;
}

// ------------------- W_f = W_ih @ W_in  fold (one-time) ---------------------
__global__ __launch_bounds__(256) void k_wf(const float* __restrict__ W_ih,
                                            const float* __restrict__ W_in,
                                            unsigned short* __restrict__ wf_att,
                                            float* __restrict__ wfx) {
  __shared__ float wl[8][512];
  int ic = blockIdx.x, jc = blockIdx.y, tid = threadIdx.x;
  for (int x = tid; x < 8 * 512; x += 256)
    wl[x >> 9][x & 511] = W_ih[(ic * 8 + (x >> 9)) * 512 + (x & 511)];
  __syncthreads();
  int j = jc * 256 + tid;
  if (j >= 1324) return;
  float acc[8] = {};
  for (int d = 0; d < 512; d++) {
    float win = W_in[d * 1324 + j];
    #pragma unroll
    for (int r = 0; r < 8; r++) acc[r] += wl[r][d] * win;
  }
  for (int r = 0; r < 8; r++) {
    int i = ic * 8 + r;
    if (j < 300) wfx[i * 300 + j] = acc[r];
    else         wf_att[i * 1024 + (j - 300)] = f2bf(acc[r]);
  }
}

__global__ __launch_bounds__(256) void k_bfull(const float* __restrict__ W_ih,
                                               const float* __restrict__ b_in,
                                               const float* __restrict__ b_ih,
                                               float* __restrict__ bfull) {
  int i = blockIdx.x * 256 + threadIdx.x;   // < 1536
  if (i >= 1536) return;
  float acc = b_ih[i];
  for (int d = 0; d < 512; d++) acc += W_ih[i * 512 + d] * b_in[d];
  bfull[i] = acc;
}

// gi_x[t*64+b, :] = expl[t,b,:300] @ Wfx^T   (all steps precomputed)
__global__ __launch_bounds__(256) void k_gix(const float* __restrict__ expl,
                                             const float* __restrict__ wfx,
                                             float* __restrict__ gi_x) {
  __shared__ float el[16][300];
  int rc = blockIdx.x, ic = blockIdx.y, tid = threadIdx.x;
  for (int x = tid; x < 16 * 300; x += 256)
    el[x / 300][x % 300] = expl[(size_t)(rc * 16 + x / 300) * 300 + (x % 300)];
  __syncthreads();
  int c = ic * 256 + tid;    // < 1536 exactly
  float acc[16] = {};
  for (int k = 0; k < 300; k++) {
    float wv = wfx[c * 300 + k];
    #pragma unroll
    for (int r = 0; r < 16; r++) acc[r] += el[r][k] * wv;
  }
  for (int r = 0; r < 16; r++) gi_x[(size_t)(rc * 16 + r) * 1536 + c] = acc[r];
}

// ------------------------------- phase X -----------------------------------
// grid 128 = (b, side). side 0/1 = attention 1/2. Does GRU elementwise for
// step t-1, then q = tanh(h Wq^T + bq), scores, softmax, att -> bf16.
__global__ __launch_bounds__(256) void k_phaseX(
    int t, const float* __restrict__ hrd, float* __restrict__ hwr,
    unsigned short* __restrict__ h_bf, const float* __restrict__ gi,
    const float* __restrict__ gh, unsigned short* __restrict__ outs_bf,
    const unsigned short* __restrict__ wq, const float* __restrict__ bq1,
    const float* __restrict__ bq2,
    const unsigned short* __restrict__ keys1, const unsigned short* __restrict__ keys2,
    const unsigned short* __restrict__ vals1, const unsigned short* __restrict__ vals2,
    unsigned short* __restrict__ att_bf)
{
  const int b = blockIdx.x >> 1, side = blockIdx.x & 1;
  const int tid = threadIdx.x;
  __shared__ float hs[512];
  __shared__ float qs[512];
  __shared__ float sred[128][2];
  __shared__ float pr[128];

  for (int d = tid; d < 512; d += 256) {
    float hv;
    if (t > 0) {
      float ir = gi[b*1536 + d], iz = gi[b*1536 + 512 + d], inn = gi[b*1536 + 1024 + d];
      float hr = gh[b*1536 + d], hz = gh[b*1536 + 512 + d], hn = gh[b*1536 + 1024 + d];
      float ho = hrd[b*512 + d];
      float r = 1.f / (1.f + expf(-(ir + hr)));
      float z = 1.f / (1.f + expf(-(iz + hz)));
      float n = tanhf(inn + r * hn);
      hv = (1.f - z) * n + z * ho;
      if (side == 0) {
        hwr[b*512 + d] = hv;
        unsigned short bf = f2bf(hv);
        h_bf[b*512 + d] = bf;
        outs_bf[(size_t)((t - 1) * 64 + b) * 512 + d] = bf;
      }
    } else {
      hv = hrd[b*512 + d];
      if (side == 0) h_bf[b*512 + d] = f2bf(hv);
    }
    hs[d] = hv;
  }
  __syncthreads();

  const unsigned short* wqi = wq + (size_t)side * 512 * 512;
  const float* bq = side ? bq2 : bq1;
  for (int a = tid; a < 512; a += 256) {
    const u16x8* wrow = (const u16x8*)(wqi + a * 512);
    float acc = 0.f;
    #pragma unroll 4
    for (int k8 = 0; k8 < 64; k8++) {
      u16x8 wv = wrow[k8];
      #pragma unroll
      for (int jj = 0; jj < 8; jj++) acc += hs[k8 * 8 + jj] * bf2f(wv[jj]);
    }
    qs[a] = tanhf(acc + bq[a]);
  }
  __syncthreads();

  const unsigned short* keys = side ? keys2 : keys1;
  {
    int tt = tid >> 1, half = tid & 1;
    const u16x8* krow = (const u16x8*)(keys + ((size_t)tt * 64 + b) * 512 + half * 256);
    float acc = 0.f;
    #pragma unroll 4
    for (int k8 = 0; k8 < 32; k8++) {
      u16x8 kv = krow[k8];
      #pragma unroll
      for (int jj = 0; jj < 8; jj++) acc += qs[half * 256 + k8 * 8 + jj] * bf2f(kv[jj]);
    }
    sred[tt][half] = acc;
  }
  __syncthreads();

  if (tid < 64) {
    float s0 = sred[tid][0] + sred[tid][1];
    float s1 = sred[tid + 64][0] + sred[tid + 64][1];
    float m = fmaxf(s0, s1);
    #pragma unroll
    for (int off = 32; off; off >>= 1) m = fmaxf(m, __shfl_xor(m, off));
    float e0 = __expf(s0 - m), e1 = __expf(s1 - m);
    float ss = e0 + e1;
    #pragma unroll
    for (int off = 32; off; off >>= 1) ss += __shfl_xor(ss, off);
    float inv = 1.f / ss;
    pr[tid] = e0 * inv;
    pr[tid + 64] = e1 * inv;
  }
  __syncthreads();

  const unsigned short* vals = side ? vals2 : vals1;
  {
    int a0 = tid * 2;
    float acc0 = 0.f, acc1 = 0.f;
    for (int tt = 0; tt < 128; tt++) {
      float p = pr[tt];
      unsigned v = *(const unsigned*)(vals + ((size_t)tt * 64 + b) * 512 + a0);
      acc0 += p * bf2f((unsigned short)(v & 0xffffu));
      acc1 += p * bf2f((unsigned short)(v >> 16));
    }
    att_bf[b * 1024 + side * 512 + a0]     = f2bf(acc0);
    att_bf[b * 1024 + side * 512 + a0 + 1] = f2bf(acc1);
  }
}

// ------------------------------- phase Y -----------------------------------
// grid 48: cb<24 -> gi tile (A=att K=1024, +gi_x+bfull); else gh tile
// (A=h_bf K=512, +b_hh). 64x64 tile, 4 waves (16 rows each).
__global__ __launch_bounds__(256) void k_phaseY(
    int t, const unsigned short* __restrict__ att_bf,
    const unsigned short* __restrict__ h_bf,
    const unsigned short* __restrict__ wf_att, const unsigned short* __restrict__ whh,
    const float* __restrict__ gi_x, const float* __restrict__ bfull,
    const float* __restrict__ b_hh, float* __restrict__ gi, float* __restrict__ gh)
{
  __shared__ __align__(16) unsigned short As[64 * 32];
  __shared__ __align__(16) unsigned short Bs[64 * 32];
  const int tid = threadIdx.x;
  const int cb = blockIdx.x;
  const bool isGi = cb < 24;
  const int n0 = (isGi ? cb : cb - 24) * 64;
  const unsigned short* A = isGi ? att_bf : h_bf;
  const unsigned short* B = isGi ? wf_att : whh;
  const int K = isGi ? 1024 : 512;
  const int lane = tid & 63, w = tid >> 6;
  const int fr = lane & 15, fq = lane >> 4;
  f32x4 acc[4] = {};
  const int srow = tid >> 2, soff = (tid & 3) * 8;

  for (int k = 0; k < K; k += 32) {
    u16x8 av = *(const u16x8*)(A + (size_t)srow * K + k + soff);
    u16x8 bv = *(const u16x8*)(B + (size_t)(n0 + srow) * K + k + soff);
    *(u16x8*)&As[srow * 32 + soff] = av;
    *(u16x8*)&Bs[srow * 32 + soff] = bv;
    __syncthreads();
    u16x8 af = *(const u16x8*)&As[(w * 16 + fr) * 32 + fq * 8];
    #pragma unroll
    for (int nj = 0; nj < 4; nj++) {
      u16x8 bfv = *(const u16x8*)&Bs[(nj * 16 + fr) * 32 + fq * 8];
      acc[nj] = __builtin_amdgcn_mfma_f32_16x16x32_bf16(as_bf(af), as_bf(bfv), acc[nj], 0, 0, 0);
    }
    __syncthreads();
  }
  float* out = isGi ? gi : gh;
  #pragma unroll
  for (int nj = 0; nj < 4; nj++) {
    #pragma unroll
    for (int j = 0; j < 4; j++) {
      int row = w * 16 + fq * 4 + j;
      int col = n0 + nj * 16 + fr;
      float v = acc[nj][j];
      if (isGi) v += gi_x[(size_t)(t * 64 + row) * 1536 + col] + bfull[col];
      else      v += b_hh[col];
      out[(size_t)row * 1536 + col] = v;
    }
  }
}

__global__ __launch_bounds__(256) void k_final(const float* __restrict__ gi,
                                               const float* __restrict__ gh,
                                               const float* __restrict__ hrd,
                                               unsigned short* __restrict__ outs_bf) {
  int b = blockIdx.x, tid = threadIdx.x;
  for (int d = tid; d < 512; d += 256) {
    float ir = gi[b*1536 + d], iz = gi[b*1536 + 512 + d], inn = gi[b*1536 + 1024 + d];
    float hr = gh[b*1536 + d], hz = gh[b*1536 + 512 + d], hn = gh[b*1536 + 1024 + d];
    float ho = hrd[b*512 + d];
    float r = 1.f / (1.f + expf(-(ir + hr)));
    float z = 1.f / (1.f + expf(-(iz + hz)));
    float n = tanhf(inn + r * hn);
    float hv = (1.f - z) * n + z * ho;
    outs_bf[(size_t)(31 * 64 + b) * 512 + d] = f2bf(hv);
  }
}

// ---------------------------------------------------------------------------
extern "C" void kernel_launch(void* const* d_in, const int* in_sizes, int n_in,
                              void* d_out, int out_size, void* d_ws, size_t ws_size,
                              hipStream_t stream) {
  const float* expl  = (const float*)d_in[0];
  const float* enc1  = (const float*)d_in[1];
  const float* enc2  = (const float*)d_in[2];
  const float* s1e   = (const float*)d_in[3];
  const float* s2e   = (const float*)d_in[4];
  const float* W_ctx = (const float*)d_in[5];
  const float* b_ctx = (const float*)d_in[6];
  const float* Wq1   = (const float*)d_in[7];
  const float* bq1   = (const float*)d_in[8];
  const float* Wk1   = (const float*)d_in[9];
  const float* bk1   = (const float*)d_in[10];
  const float* Wv1   = (const float*)d_in[11];
  const float* bv1   = (const float*)d_in[12];
  const float* Wq2   = (const float*)d_in[13];
  const float* bq2   = (const float*)d_in[14];
  const float* Wk2   = (const float*)d_in[15];
  const float* bk2   = (const float*)d_in[16];
  const float* Wv2   = (const float*)d_in[17];
  const float* bv2   = (const float*)d_in[18];
  const float* W_in  = (const float*)d_in[19];
  const float* b_in  = (const float*)d_in[20];
  const float* W_ih  = (const float*)d_in[21];
  const float* b_ih  = (const float*)d_in[22];
  const float* W_hh  = (const float*)d_in[23];
  const float* b_hh  = (const float*)d_in[24];
  const float* W_voc = (const float*)d_in[25];
  const float* b_voc = (const float*)d_in[26];
  float* out = (float*)d_out;

  char* ws = (char*)d_ws;
  unsigned short* keys1  = (unsigned short*)(ws + 0);
  unsigned short* vals1  = (unsigned short*)(ws + 8388608);
  unsigned short* keys2  = (unsigned short*)(ws + 16777216);
  unsigned short* vals2  = (unsigned short*)(ws + 25165824);
  unsigned short* wvoc   = (unsigned short*)(ws + 33554432);
  unsigned short* wkv1   = (unsigned short*)(ws + 66322432);
  unsigned short* wkv2   = (unsigned short*)(ws + 74711040);
  unsigned short* whh    = (unsigned short*)(ws + 83099648);
  unsigned short* wq     = (unsigned short*)(ws + 84672512);
  unsigned short* wf_att = (unsigned short*)(ws + 85721088);
  float*          wfx    = (float*)(ws + 88866816);
  float*          bfull  = (float*)(ws + 90710016);
  float*          gi_x   = (float*)(ws + 90716160);
  unsigned short* ctx_bf = (unsigned short*)(ws + 103299072);
  float*          part   = (float*)(ws + 105396224);
  float*          hA     = (float*)(ws + 106444800);
  float*          hB     = (float*)(ws + 106575872);
  unsigned short* h_bf   = (unsigned short*)(ws + 106706944);
  unsigned short* att_bf = (unsigned short*)(ws + 106772480);
  float*          gi     = (float*)(ws + 106903552);
  float*          gh     = (float*)(ws + 107296768);
  unsigned short* outs_bf= (unsigned short*)(ws + 107689984);
  // total ws use ~109.8 MB

  auto cvt = [&](const float* s, unsigned short* d, int n) {
    k_cvt<<<(n + 1023) / 1024, 256, 0, stream>>>(s, d, n);
  };
  cvt(Wk1, wkv1, 512 * 4096);
  cvt(Wv1, wkv1 + 512 * 4096, 512 * 4096);
  cvt(Wk2, wkv2, 512 * 4096);
  cvt(Wv2, wkv2 + 512 * 4096, 512 * 4096);
  cvt(W_voc, wvoc, 32000 * 512);
  cvt(W_hh, whh, 1536 * 512);
  cvt(Wq1, wq, 512 * 512);
  cvt(Wq2, wq + 512 * 512, 512 * 512);

  k_build_ctx<<<4096, 256, 0, stream>>>(s1e, s2e, ctx_bf);

  // h0 = ctx_feat @ W_ctx^T + b_ctx   (split-K=8 -> partials -> reduce to hA)
  k_gemm128<1, 0, 2><<<dim3(4, 1, 8), 256, 0, stream>>>(
      ctx_bf, 16384, W_ctx, 16384, 64, 512, 2048,
      nullptr, nullptr, part, nullptr, nullptr);
  k_reduce_h0<<<128, 256, 0, stream>>>(part, b_ctx, hA);

  // keys/vals = tanh(enc @ [Wk|Wv]^T + b)
  k_gemm128<0, 1, 0><<<dim3(8, 64, 1), 256, 0, stream>>>(
      enc1, 4096, wkv1, 4096, 8192, 1024, 4096, keys1, vals1, nullptr, bk1, bv1);
  k_gemm128<0, 1, 0><<<dim3(8, 64, 1), 256, 0, stream>>>(
      enc2, 4096, wkv2, 4096, 8192, 1024, 4096, keys2, vals2, nullptr, bk2, bv2);

  k_wf<<<dim3(192, 6), 256, 0, stream>>>(W_ih, W_in, wf_att, wfx);
  k_bfull<<<6, 256, 0, stream>>>(W_ih, b_in, b_ih, bfull);
  k_gix<<<dim3(128, 6), 256, 0, stream>>>(expl, wfx, gi_x);

  float* harr[2] = { hB, hA };
  for (int t = 0; t < 32; t++) {
    const float* hrd = (t == 0) ? hA : harr[t & 1];
    float* hwr = harr[(t + 1) & 1];
    k_phaseX<<<128, 256, 0, stream>>>(t, hrd, hwr, h_bf, gi, gh, outs_bf,
                                      wq, bq1, bq2, keys1, keys2, vals1, vals2, att_bf);
    k_phaseY<<<48, 256, 0, stream>>>(t, att_bf, h_bf, wf_att, whh,
                                     gi_x, bfull, b_hh, gi, gh);
  }
  k_final<<<64, 256, 0, stream>>>(gi, gh, hB, outs_bf);

  // logits = outs @ W_voc^T + b_voc
  k_gemm128<1, 1, 1><<<dim3(250, 16, 1), 256, 0, stream>>>(
      outs_bf, 512, wvoc, 512, 2048, 32000, 512,
      nullptr, nullptr, out, b_voc, nullptr);
}

// Round 3
// 2251.296 us; speedup vs baseline: 1.0903x; 1.0903x over previous
//
#include <hip/hip_runtime.h>

// ---------------------------------------------------------------------------
// AttentionDecoder: 32-step GRU decoder with dual dot-product attention.
//   prologue: enc->bf16 cvt; keys/vals GEMMs (global_load_lds, XCD-aware grid);
//             ctx->h0; W_f = W_ih@W_in fold; gi_x precompute
//   loop t=0..31: phaseX (GRU elementwise, q, softmax attn), phaseY (gi/gh MFMA)
//   epilogue: final GRU; vocab GEMM (global_load_lds) -> d_out (f32)
// ws aliasing: encbf region is reused for all post-kv buffers (stream-ordered).
// ---------------------------------------------------------------------------

typedef float    f32x4 __attribute__((ext_vector_type(4)));
typedef __bf16   bf16x8 __attribute__((ext_vector_type(8)));
typedef unsigned short u16x8 __attribute__((ext_vector_type(8)));

#define DEV __device__ __forceinline__

DEV unsigned short f2bf(float f) {
  unsigned u = __builtin_bit_cast(unsigned, f);
  u += 0x7fffu + ((u >> 16) & 1u);               // round-to-nearest-even
  return (unsigned short)(u >> 16);
}
DEV float bf2f(unsigned short h) {
  return __builtin_bit_cast(float, (unsigned)h << 16);
}
DEV bf16x8 as_bf(u16x8 v) { return __builtin_bit_cast(bf16x8, v); }
DEV u16x8 zero8() {
  u16x8 r = {0, 0, 0, 0, 0, 0, 0, 0};
  return r;
}
DEV u16x8 pack8(float4 a, float4 b) {
  u16x8 r;
  r[0]=f2bf(a.x); r[1]=f2bf(a.y); r[2]=f2bf(a.z); r[3]=f2bf(a.w);
  r[4]=f2bf(b.x); r[5]=f2bf(b.y); r[6]=f2bf(b.z); r[7]=f2bf(b.w);
  return r;
}
DEV void gload16(const void* g, void* l) {
  __builtin_amdgcn_global_load_lds(
      (const __attribute__((address_space(1))) void*)g,
      (__attribute__((address_space(3))) void*)l, 16, 0, 0);
}

// ------------------------------- converts ----------------------------------
__global__ __launch_bounds__(256) void k_cvt(const float* __restrict__ s,
                                             unsigned short* __restrict__ d, int n) {
  int i = (blockIdx.x * 256 + threadIdx.x) * 4;
  if (i + 4 <= n) {
    float4 v = *(const float4*)(s + i);
    d[i] = f2bf(v.x); d[i+1] = f2bf(v.y); d[i+2] = f2bf(v.z); d[i+3] = f2bf(v.w);
  } else {
    for (; i < n; i++) d[i] = f2bf(s[i]);
  }
}

// ctx_feat = [s1, s2, |s1-s2|, s1*s2]  -> bf16 [64, 16384]
__global__ __launch_bounds__(256) void k_build_ctx(const float* __restrict__ s1,
                                                   const float* __restrict__ s2,
                                                   unsigned short* __restrict__ ctx) {
  int j = blockIdx.x * 256 + threadIdx.x;     // < 64*16384
  int b = j >> 14, jj = j & 16383;
  int f = jj >> 12, k = jj & 4095;
  float a = s1[b * 4096 + k], c = s2[b * 4096 + k];
  float v = (f == 0) ? a : (f == 1) ? c : (f == 2) ? fabsf(a - c) : a * c;
  ctx[j] = f2bf(v);
}

// --------------- bf16 128x128 GEMM with global_load_lds staging -------------
// C[M,N] = A[M,K] * B[N,K]^T, all dims multiples of 128 (K mult of 32).
// grid (M/128, N/128): row-block on x so col-blocks sharing an A panel land on
// one XCD (y strides are multiples of 8 in linear id). EPI 0: tanh(+bias)
// split at col 512 -> two bf16 buffers. EPI 1: +bias -> f32 (ld = ofld).
template<int EPI>
__global__ __launch_bounds__(256) void k_gemm_lds(
    const unsigned short* __restrict__ A, int lda,
    const unsigned short* __restrict__ B, int ldb, int K,
    unsigned short* __restrict__ obf0, unsigned short* __restrict__ obf1,
    float* __restrict__ of, int ofld,
    const float* __restrict__ bias0, const float* __restrict__ bias1)
{
  __shared__ __align__(16) unsigned short As[128 * 32];
  __shared__ __align__(16) unsigned short Bs[128 * 32];
  const int tid = threadIdx.x;
  const int r0 = blockIdx.x * 128, c0 = blockIdx.y * 128;
  const int lane = tid & 63, w = tid >> 6;
  const int wr = w >> 1, wc = w & 1;
  const int fr = lane & 15, fq = lane >> 4;
  f32x4 acc[4][4] = {};

  const int srow = tid >> 2, scol = (tid & 3) * 8;   // 64 rows x 4 chunks/row
  const unsigned short* gA0 = A + (size_t)(r0 + srow) * lda + scol;
  const unsigned short* gA1 = A + (size_t)(r0 + 64 + srow) * lda + scol;
  const unsigned short* gB0 = B + (size_t)(c0 + srow) * ldb + scol;
  const unsigned short* gB1 = B + (size_t)(c0 + 64 + srow) * ldb + scol;
  unsigned short* lA0 = As + tid * 8;
  unsigned short* lA1 = As + 2048 + tid * 8;
  unsigned short* lB0 = Bs + tid * 8;
  unsigned short* lB1 = Bs + 2048 + tid * 8;

  for (int k = 0; k < K; k += 32) {
    gload16(gA0 + k, lA0);
    gload16(gA1 + k, lA1);
    gload16(gB0 + k, lB0);
    gload16(gB1 + k, lB1);
    __syncthreads();

    u16x8 af[4], bfv[4];
    #pragma unroll
    for (int mi = 0; mi < 4; mi++)
      af[mi] = *(const u16x8*)&As[(wr * 64 + mi * 16 + fr) * 32 + fq * 8];
    #pragma unroll
    for (int nj = 0; nj < 4; nj++)
      bfv[nj] = *(const u16x8*)&Bs[(wc * 64 + nj * 16 + fr) * 32 + fq * 8];
    #pragma unroll
    for (int mi = 0; mi < 4; mi++)
      #pragma unroll
      for (int nj = 0; nj < 4; nj++)
        acc[mi][nj] = __builtin_amdgcn_mfma_f32_16x16x32_bf16(
            as_bf(af[mi]), as_bf(bfv[nj]), acc[mi][nj], 0, 0, 0);
    __syncthreads();
  }

  #pragma unroll
  for (int mi = 0; mi < 4; mi++)
  #pragma unroll
  for (int nj = 0; nj < 4; nj++) {
    f32x4 a = acc[mi][nj];
    #pragma unroll
    for (int j = 0; j < 4; j++) {
      int grow = r0 + wr * 64 + mi * 16 + fq * 4 + j;
      int gcol = c0 + wc * 64 + nj * 16 + fr;
      float v = a[j];
      if constexpr (EPI == 0) {
        float bias = gcol < 512 ? bias0[gcol] : bias1[gcol - 512];
        unsigned short r = f2bf(tanhf(v + bias));
        (gcol < 512 ? obf0 : obf1)[(size_t)grow * 512 + (gcol & 511)] = r;
      } else {
        of[(size_t)grow * ofld + gcol] = v + bias0[gcol];
      }
    }
  }
}

// ------------------------- generic 128x128 MFMA GEMM ------------------------
// (kept for h0 only: A bf16, B f32, EPI 2 raw partials via z split-K)
template<int A_BF16, int B_BF16, int EPI>
__global__ __launch_bounds__(256) void k_gemm128(
    const void* __restrict__ Ap, int lda, const void* __restrict__ Bp, int ldb,
    int M, int N, int kper,
    unsigned short* __restrict__ obf0, unsigned short* __restrict__ obf1,
    float* __restrict__ of, const float* __restrict__ bias0,
    const float* __restrict__ bias1)
{
  __shared__ __align__(16) unsigned short As[128 * 32];
  __shared__ __align__(16) unsigned short Bs[128 * 32];
  const int tid = threadIdx.x;
  const int c0 = blockIdx.x * 128, r0 = blockIdx.y * 128;
  const int k0 = blockIdx.z * kper;
  if (EPI == 2) of += (size_t)blockIdx.z * M * N;

  const int lane = tid & 63, w = tid >> 6;
  const int wr = w >> 1, wc = w & 1;
  const int fr = lane & 15, fq = lane >> 4;

  f32x4 acc[4][4] = {};

  const int srow = tid >> 1, shalf = (tid & 1) * 16;

  for (int k = k0; k < k0 + kper; k += 32) {
    u16x8 a0, a1, b0, b1;
    {
      int gr = r0 + srow;
      if (gr < M) {
        if (A_BF16) {
          const unsigned short* a = (const unsigned short*)Ap + (size_t)gr * lda + k + shalf;
          a0 = *(const u16x8*)a; a1 = *(const u16x8*)(a + 8);
        } else {
          const float* a = (const float*)Ap + (size_t)gr * lda + k + shalf;
          float4 f0 = ((const float4*)a)[0], f1 = ((const float4*)a)[1];
          float4 f2 = ((const float4*)a)[2], f3 = ((const float4*)a)[3];
          a0 = pack8(f0, f1); a1 = pack8(f2, f3);
        }
      } else { a0 = zero8(); a1 = zero8(); }
    }
    {
      int gr = c0 + srow;
      if (B_BF16) {
        const unsigned short* p = (const unsigned short*)Bp + (size_t)gr * ldb + k + shalf;
        b0 = *(const u16x8*)p; b1 = *(const u16x8*)(p + 8);
      } else {
        const float* p = (const float*)Bp + (size_t)gr * ldb + k + shalf;
        float4 f0 = ((const float4*)p)[0], f1 = ((const float4*)p)[1];
        float4 f2 = ((const float4*)p)[2], f3 = ((const float4*)p)[3];
        b0 = pack8(f0, f1); b1 = pack8(f2, f3);
      }
    }
    *(u16x8*)&As[srow * 32 + shalf]     = a0;
    *(u16x8*)&As[srow * 32 + shalf + 8] = a1;
    *(u16x8*)&Bs[srow * 32 + shalf]     = b0;
    *(u16x8*)&Bs[srow * 32 + shalf + 8] = b1;
    __syncthreads();

    u16x8 af[4], bfv[4];
    #pragma unroll
    for (int mi = 0; mi < 4; mi++)
      af[mi] = *(const u16x8*)&As[(wr * 64 + mi * 16 + fr) * 32 + fq * 8];
    #pragma unroll
    for (int nj = 0; nj < 4; nj++)
      bfv[nj] = *(const u16x8*)&Bs[(wc * 64 + nj * 16 + fr) * 32 + fq * 8];
    #pragma unroll
    for (int mi = 0; mi < 4; mi++)
      #pragma unroll
      for (int nj = 0; nj < 4; nj++)
        acc[mi][nj] = __builtin_amdgcn_mfma_f32_16x16x32_bf16(
            as_bf(af[mi]), as_bf(bfv[nj]), acc[mi][nj], 0, 0, 0);
    __syncthreads();
  }

  #pragma unroll
  for (int mi = 0; mi < 4; mi++)
  #pragma unroll
  for (int nj = 0; nj < 4; nj++) {
    f32x4 a = acc[mi][nj];
    #pragma unroll
    for (int j = 0; j < 4; j++) {
      int grow = r0 + wr * 64 + mi * 16 + fq * 4 + j;
      int gcol = c0 + wc * 64 + nj * 16 + fr;
      if (grow < M) {
        float v = a[j];
        if constexpr (EPI == 0) {
          float bias = gcol < 512 ? bias0[gcol] : bias1[gcol - 512];
          unsigned short r = f2bf(tanhf(v + bias));
          (gcol < 512 ? obf0 : obf1)[(size_t)grow * 512 + (gcol & 511)] = r;
        } else if constexpr (EPI == 1) {
          of[(size_t)grow * N + gcol] = v + bias0[gcol];
        } else {
          of[(size_t)grow * N + gcol] = v;
        }
      }
    }
  }
}

__global__ __launch_bounds__(256) void k_reduce_h0(const float* __restrict__ part,
                                                   const float* __restrict__ b_ctx,
                                                   float* __restrict__ h) {
  int j = blockIdx.x * 256 + threadIdx.x;   // < 64*512
  float s = b_ctx[j & 511];
  for (int z = 0; z < 8; z++) s += part[z * 32768 + j];
  h[j] = s;
}

// ------------------- W_f = W_ih @ W_in  fold (one-time) ---------------------
__global__ __launch_bounds__(256) void k_wf(const float* __restrict__ W_ih,
                                            const float* __restrict__ W_in,
                                            unsigned short* __restrict__ wf_att,
                                            float* __restrict__ wfx) {
  __shared__ float wl[8][512];
  int ic = blockIdx.x, jc = blockIdx.y, tid = threadIdx.x;
  for (int x = tid; x < 8 * 512; x += 256)
    wl[x >> 9][x & 511] = W_ih[(ic * 8 + (x >> 9)) * 512 + (x & 511)];
  __syncthreads();
  int j = jc * 256 + tid;
  if (j >= 1324) return;
  float acc[8] = {};
  for (int d = 0; d < 512; d++) {
    float win = W_in[d * 1324 + j];
    #pragma unroll
    for (int r = 0; r < 8; r++) acc[r] += wl[r][d] * win;
  }
  for (int r = 0; r < 8; r++) {
    int i = ic * 8 + r;
    if (j < 300) wfx[i * 300 + j] = acc[r];
    else         wf_att[i * 1024 + (j - 300)] = f2bf(acc[r]);
  }
}

__global__ __launch_bounds__(256) void k_bfull(const float* __restrict__ W_ih,
                                               const float* __restrict__ b_in,
                                               const float* __restrict__ b_ih,
                                               float* __restrict__ bfull) {
  int i = blockIdx.x * 256 + threadIdx.x;   // < 1536
  if (i >= 1536) return;
  float acc = b_ih[i];
  for (int d = 0; d < 512; d++) acc += W_ih[i * 512 + d] * b_in[d];
  bfull[i] = acc;
}

// gi_x[t*64+b, :] = expl[t,b,:300] @ Wfx^T   (all steps precomputed)
__global__ __launch_bounds__(256) void k_gix(const float* __restrict__ expl,
                                             const float* __restrict__ wfx,
                                             float* __restrict__ gi_x) {
  __shared__ float el[16][300];
  int rc = blockIdx.x, ic = blockIdx.y, tid = threadIdx.x;
  for (int x = tid; x < 16 * 300; x += 256)
    el[x / 300][x % 300] = expl[(size_t)(rc * 16 + x / 300) * 300 + (x % 300)];
  __syncthreads();
  int c = ic * 256 + tid;    // < 1536 exactly
  float acc[16] = {};
  for (int k = 0; k < 300; k++) {
    float wv = wfx[c * 300 + k];
    #pragma unroll
    for (int r = 0; r < 16; r++) acc[r] += el[r][k] * wv;
  }
  for (int r = 0; r < 16; r++) gi_x[(size_t)(rc * 16 + r) * 1536 + c] = acc[r];
}

// ------------------------------- phase X -----------------------------------
__global__ __launch_bounds__(256) void k_phaseX(
    int t, const float* __restrict__ hrd, float* __restrict__ hwr,
    unsigned short* __restrict__ h_bf, const float* __restrict__ gi,
    const float* __restrict__ gh, unsigned short* __restrict__ outs_bf,
    const unsigned short* __restrict__ wq, const float* __restrict__ bq1,
    const float* __restrict__ bq2,
    const unsigned short* __restrict__ keys1, const unsigned short* __restrict__ keys2,
    const unsigned short* __restrict__ vals1, const unsigned short* __restrict__ vals2,
    unsigned short* __restrict__ att_bf)
{
  const int b = blockIdx.x >> 1, side = blockIdx.x & 1;
  const int tid = threadIdx.x;
  __shared__ float hs[512];
  __shared__ float qs[512];
  __shared__ float sred[128][2];
  __shared__ float pr[128];

  for (int d = tid; d < 512; d += 256) {
    float hv;
    if (t > 0) {
      float ir = gi[b*1536 + d], iz = gi[b*1536 + 512 + d], inn = gi[b*1536 + 1024 + d];
      float hr = gh[b*1536 + d], hz = gh[b*1536 + 512 + d], hn = gh[b*1536 + 1024 + d];
      float ho = hrd[b*512 + d];
      float r = 1.f / (1.f + expf(-(ir + hr)));
      float z = 1.f / (1.f + expf(-(iz + hz)));
      float n = tanhf(inn + r * hn);
      hv = (1.f - z) * n + z * ho;
      if (side == 0) {
        hwr[b*512 + d] = hv;
        unsigned short bf = f2bf(hv);
        h_bf[b*512 + d] = bf;
        outs_bf[(size_t)((t - 1) * 64 + b) * 512 + d] = bf;
      }
    } else {
      hv = hrd[b*512 + d];
      if (side == 0) h_bf[b*512 + d] = f2bf(hv);
    }
    hs[d] = hv;
  }
  __syncthreads();

  const unsigned short* wqi = wq + (size_t)side * 512 * 512;
  const float* bq = side ? bq2 : bq1;
  for (int a = tid; a < 512; a += 256) {
    const u16x8* wrow = (const u16x8*)(wqi + a * 512);
    float acc = 0.f;
    #pragma unroll 4
    for (int k8 = 0; k8 < 64; k8++) {
      u16x8 wv = wrow[k8];
      #pragma unroll
      for (int jj = 0; jj < 8; jj++) acc += hs[k8 * 8 + jj] * bf2f(wv[jj]);
    }
    qs[a] = tanhf(acc + bq[a]);
  }
  __syncthreads();

  const unsigned short* keys = side ? keys2 : keys1;
  {
    int tt = tid >> 1, half = tid & 1;
    const u16x8* krow = (const u16x8*)(keys + ((size_t)tt * 64 + b) * 512 + half * 256);
    float acc = 0.f;
    #pragma unroll 4
    for (int k8 = 0; k8 < 32; k8++) {
      u16x8 kv = krow[k8];
      #pragma unroll
      for (int jj = 0; jj < 8; jj++) acc += qs[half * 256 + k8 * 8 + jj] * bf2f(kv[jj]);
    }
    sred[tt][half] = acc;
  }
  __syncthreads();

  if (tid < 64) {
    float s0 = sred[tid][0] + sred[tid][1];
    float s1 = sred[tid + 64][0] + sred[tid + 64][1];
    float m = fmaxf(s0, s1);
    #pragma unroll
    for (int off = 32; off; off >>= 1) m = fmaxf(m, __shfl_xor(m, off));
    float e0 = __expf(s0 - m), e1 = __expf(s1 - m);
    float ss = e0 + e1;
    #pragma unroll
    for (int off = 32; off; off >>= 1) ss += __shfl_xor(ss, off);
    float inv = 1.f / ss;
    pr[tid] = e0 * inv;
    pr[tid + 64] = e1 * inv;
  }
  __syncthreads();

  const unsigned short* vals = side ? vals2 : vals1;
  {
    int a0 = tid * 2;
    float acc0 = 0.f, acc1 = 0.f;
    for (int tt = 0; tt < 128; tt++) {
      float p = pr[tt];
      unsigned v = *(const unsigned*)(vals + ((size_t)tt * 64 + b) * 512 + a0);
      acc0 += p * bf2f((unsigned short)(v & 0xffffu));
      acc1 += p * bf2f((unsigned short)(v >> 16));
    }
    att_bf[b * 1024 + side * 512 + a0]     = f2bf(acc0);
    att_bf[b * 1024 + side * 512 + a0 + 1] = f2bf(acc1);
  }
}

// ------------------------------- phase Y -----------------------------------
__global__ __launch_bounds__(256) void k_phaseY(
    int t, const unsigned short* __restrict__ att_bf,
    const unsigned short* __restrict__ h_bf,
    const unsigned short* __restrict__ wf_att, const unsigned short* __restrict__ whh,
    const float* __restrict__ gi_x, const float* __restrict__ bfull,
    const float* __restrict__ b_hh, float* __restrict__ gi, float* __restrict__ gh)
{
  __shared__ __align__(16) unsigned short As[64 * 32];
  __shared__ __align__(16) unsigned short Bs[64 * 32];
  const int tid = threadIdx.x;
  const int cb = blockIdx.x;
  const bool isGi = cb < 24;
  const int n0 = (isGi ? cb : cb - 24) * 64;
  const unsigned short* A = isGi ? att_bf : h_bf;
  const unsigned short* B = isGi ? wf_att : whh;
  const int K = isGi ? 1024 : 512;
  const int lane = tid & 63, w = tid >> 6;
  const int fr = lane & 15, fq = lane >> 4;
  f32x4 acc[4] = {};
  const int srow = tid >> 2, soff = (tid & 3) * 8;

  for (int k = 0; k < K; k += 32) {
    u16x8 av = *(const u16x8*)(A + (size_t)srow * K + k + soff);
    u16x8 bv = *(const u16x8*)(B + (size_t)(n0 + srow) * K + k + soff);
    *(u16x8*)&As[srow * 32 + soff] = av;
    *(u16x8*)&Bs[srow * 32 + soff] = bv;
    __syncthreads();
    u16x8 af = *(const u16x8*)&As[(w * 16 + fr) * 32 + fq * 8];
    #pragma unroll
    for (int nj = 0; nj < 4; nj++) {
      u16x8 bfv = *(const u16x8*)&Bs[(nj * 16 + fr) * 32 + fq * 8];
      acc[nj] = __builtin_amdgcn_mfma_f32_16x16x32_bf16(as_bf(af), as_bf(bfv), acc[nj], 0, 0, 0);
    }
    __syncthreads();
  }
  float* out = isGi ? gi : gh;
  #pragma unroll
  for (int nj = 0; nj < 4; nj++) {
    #pragma unroll
    for (int j = 0; j < 4; j++) {
      int row = w * 16 + fq * 4 + j;
      int col = n0 + nj * 16 + fr;
      float v = acc[nj][j];
      if (isGi) v += gi_x[(size_t)(t * 64 + row) * 1536 + col] + bfull[col];
      else      v += b_hh[col];
      out[(size_t)row * 1536 + col] = v;
    }
  }
}

__global__ __launch_bounds__(256) void k_final(const float* __restrict__ gi,
                                               const float* __restrict__ gh,
                                               const float* __restrict__ hrd,
                                               unsigned short* __restrict__ outs_bf) {
  int b = blockIdx.x, tid = threadIdx.x;
  for (int d = tid; d < 512; d += 256) {
    float ir = gi[b*1536 + d], iz = gi[b*1536 + 512 + d], inn = gi[b*1536 + 1024 + d];
    float hr = gh[b*1536 + d], hz = gh[b*1536 + 512 + d], hn = gh[b*1536 + 1024 + d];
    float ho = hrd[b*512 + d];
    float r = 1.f / (1.f + expf(-(ir + hr)));
    float z = 1.f / (1.f + expf(-(iz + hz)));
    float n = tanhf(inn + r * hn);
    float hv = (1.f - z) * n + z * ho;
    outs_bf[(size_t)(31 * 64 + b) * 512 + d] = f2bf(hv);
  }
}

// ---------------------------------------------------------------------------
extern "C" void kernel_launch(void* const* d_in, const int* in_sizes, int n_in,
                              void* d_out, int out_size, void* d_ws, size_t ws_size,
                              hipStream_t stream) {
  const float* expl  = (const float*)d_in[0];
  const float* enc1  = (const float*)d_in[1];
  const float* enc2  = (const float*)d_in[2];
  const float* s1e   = (const float*)d_in[3];
  const float* s2e   = (const float*)d_in[4];
  const float* W_ctx = (const float*)d_in[5];
  const float* b_ctx = (const float*)d_in[6];
  const float* Wq1   = (const float*)d_in[7];
  const float* bq1   = (const float*)d_in[8];
  const float* Wk1   = (const float*)d_in[9];
  const float* bk1   = (const float*)d_in[10];
  const float* Wv1   = (const float*)d_in[11];
  const float* bv1   = (const float*)d_in[12];
  const float* Wq2   = (const float*)d_in[13];
  const float* bq2   = (const float*)d_in[14];
  const float* Wk2   = (const float*)d_in[15];
  const float* bk2   = (const float*)d_in[16];
  const float* Wv2   = (const float*)d_in[17];
  const float* bv2   = (const float*)d_in[18];
  const float* W_in  = (const float*)d_in[19];
  const float* b_in  = (const float*)d_in[20];
  const float* W_ih  = (const float*)d_in[21];
  const float* b_ih  = (const float*)d_in[22];
  const float* W_hh  = (const float*)d_in[23];
  const float* b_hh  = (const float*)d_in[24];
  const float* W_voc = (const float*)d_in[25];
  const float* b_voc = (const float*)d_in[26];
  float* out = (float*)d_out;

  char* ws = (char*)d_ws;
  // persistent through prologue: keys/vals outputs
  unsigned short* keys1  = (unsigned short*)(ws + 0);
  unsigned short* vals1  = (unsigned short*)(ws + 8388608);
  unsigned short* keys2  = (unsigned short*)(ws + 16777216);
  unsigned short* vals2  = (unsigned short*)(ws + 25165824);
  // enc bf16 staging region [33554432, 100663296) — reused per side, then
  // reused again (stream-ordered) for all post-kv buffers below.
  unsigned short* encbf  = (unsigned short*)(ws + 33554432);
  unsigned short* wkv    = (unsigned short*)(ws + 100663296);  // 8.4 MB, per side
  // post-kv region (aliases encbf):
  const size_t S = 33554432;
  unsigned short* wvoc   = (unsigned short*)(ws + S + 0);
  unsigned short* whh    = (unsigned short*)(ws + S + 32768000);
  unsigned short* wq     = (unsigned short*)(ws + S + 34340864);
  unsigned short* wf_att = (unsigned short*)(ws + S + 35389440);
  float*          wfx    = (float*)(ws + S + 38535168);
  float*          bfull  = (float*)(ws + S + 40378368);
  float*          gi_x   = (float*)(ws + S + 40384512);
  unsigned short* ctx_bf = (unsigned short*)(ws + S + 52967424);
  float*          part   = (float*)(ws + S + 55064576);
  float*          hA     = (float*)(ws + S + 56113152);
  float*          hB     = (float*)(ws + S + 56244224);
  unsigned short* h_bf   = (unsigned short*)(ws + S + 56375296);
  unsigned short* att_bf = (unsigned short*)(ws + S + 56440832);
  float*          gi     = (float*)(ws + S + 56571904);
  float*          gh     = (float*)(ws + S + 56965120);
  unsigned short* outs_bf= (unsigned short*)(ws + S + 57358336);
  // peak ws use: 100663296 + 8388608 = ~109.1 MB (known-good <= R2's 109.8)

  auto cvt = [&](const float* s, unsigned short* d, int n) {
    k_cvt<<<(n + 1023) / 1024, 256, 0, stream>>>(s, d, n);
  };

  // ---- keys/vals side 1 ----
  cvt(enc1, encbf, 8192 * 4096);
  cvt(Wk1, wkv, 512 * 4096);
  cvt(Wv1, wkv + 512 * 4096, 512 * 4096);
  k_gemm_lds<0><<<dim3(64, 8), 256, 0, stream>>>(
      encbf, 4096, wkv, 4096, 4096, keys1, vals1, nullptr, 0, bk1, bv1);
  // ---- keys/vals side 2 (reuses encbf/wkv) ----
  cvt(enc2, encbf, 8192 * 4096);
  cvt(Wk2, wkv, 512 * 4096);
  cvt(Wv2, wkv + 512 * 4096, 512 * 4096);
  k_gemm_lds<0><<<dim3(64, 8), 256, 0, stream>>>(
      encbf, 4096, wkv, 4096, 4096, keys2, vals2, nullptr, 0, bk2, bv2);

  // ---- post-kv prologue (aliases encbf region; stream-ordered) ----
  cvt(W_voc, wvoc, 32000 * 512);
  cvt(W_hh, whh, 1536 * 512);
  cvt(Wq1, wq, 512 * 512);
  cvt(Wq2, wq + 512 * 512, 512 * 512);

  k_build_ctx<<<4096, 256, 0, stream>>>(s1e, s2e, ctx_bf);
  k_gemm128<1, 0, 2><<<dim3(4, 1, 8), 256, 0, stream>>>(
      ctx_bf, 16384, W_ctx, 16384, 64, 512, 2048,
      nullptr, nullptr, part, nullptr, nullptr);
  k_reduce_h0<<<128, 256, 0, stream>>>(part, b_ctx, hA);

  k_wf<<<dim3(192, 6), 256, 0, stream>>>(W_ih, W_in, wf_att, wfx);
  k_bfull<<<6, 256, 0, stream>>>(W_ih, b_in, b_ih, bfull);
  k_gix<<<dim3(128, 6), 256, 0, stream>>>(expl, wfx, gi_x);

  float* harr[2] = { hB, hA };
  for (int t = 0; t < 32; t++) {
    const float* hrd = (t == 0) ? hA : harr[t & 1];
    float* hwr = harr[(t + 1) & 1];
    k_phaseX<<<128, 256, 0, stream>>>(t, hrd, hwr, h_bf, gi, gh, outs_bf,
                                      wq, bq1, bq2, keys1, keys2, vals1, vals2, att_bf);
    k_phaseY<<<48, 256, 0, stream>>>(t, att_bf, h_bf, wf_att, whh,
                                     gi_x, bfull, b_hh, gi, gh);
  }
  k_final<<<64, 256, 0, stream>>>(gi, gh, hB, outs_bf);

  // logits = outs @ W_voc^T + b_voc  (row-block on x for XCD locality)
  k_gemm_lds<1><<<dim3(16, 250), 256, 0, stream>>>(
      outs_bf, 512, wvoc, 512, 512, nullptr, nullptr, out, 32000, b_voc, nullptr);
}